// Round 1
// baseline (1630.033 us; speedup 1.0000x reference)
//
#include <hip/hip_runtime.h>
#include <hip/hip_bf16.h>

#define NROW 16384
#define NFEATC 512
#define NH1 256
#define NH2 128
#define NCLS 8

typedef __attribute__((ext_vector_type(8))) short short8;
typedef __attribute__((ext_vector_type(4))) float f32x4;

__device__ __forceinline__ ushort f2bf(float f) {
  union { float f; unsigned u; } v; v.f = f;
  unsigned r = v.u + 0x7FFFu + ((v.u >> 16) & 1u);
  return (ushort)(r >> 16);
}
__device__ __forceinline__ float bf2f(ushort h) {
  union { unsigned u; float f; } v; v.u = ((unsigned)h) << 16; return v.f;
}

// in [K][N] fp32 -> out [N][K] bf16
__global__ __launch_bounds__(256) void transpose_conv(
    const float* __restrict__ in, ushort* __restrict__ out, int K, int N) {
  int idx = blockIdx.x * 256 + threadIdx.x;
  if (idx < K * N) {
    int k = idx / N, n = idx % N;
    out[(size_t)n * K + k] = f2bf(in[idx]);
  }
}

// C[M][N] = A[M][K] @ BT[N][K]^T ; A fp32 (cvt->bf16) or bf16 ; BT bf16 (k-contiguous)
// STORET: Out[N][M] bf16 plain. else: Out[M][N] bf16 = relu(acc + bias[col]).
template<int BM, int BN, int WM, int WN, bool AFP32, bool STORET>
__global__ __launch_bounds__(256) void gemm_bf16(
    const void* __restrict__ Ap, const ushort* __restrict__ BT,
    ushort* __restrict__ Out, const float* __restrict__ bias,
    int M, int N, int K)
{
  constexpr int BK = 32, LDSK = BK + 8;
  constexpr int MR = WM / 16, NR = WN / 16;
  constexpr int nWc = BN / WN;
  static_assert((BM / WM) * (BN / WN) == 4, "4 waves");
  __shared__ ushort As[BM * LDSK];
  __shared__ ushort Bs[BN * LDSK];

  const int t = threadIdx.x;
  const int l = t & 63;
  const int wid = t >> 6;
  const int wr0 = (wid / nWc) * WM;
  const int wc0 = (wid % nWc) * WN;
  const int bm0 = blockIdx.x * BM;
  const int bn0 = blockIdx.y * BN;

  constexpr int AELEM = BM * BK / 256;   // bf16 elems staged per thread (A)
  constexpr int ATPR = BK / AELEM;       // threads per A row
  const int ar = t / ATPR, ak = (t % ATPR) * AELEM;
  constexpr int BELEM = BN * BK / 256;
  constexpr int BTPR = BK / BELEM;
  const int br = t / BTPR, bk = (t % BTPR) * BELEM;

  const float* Af = (const float*)Ap;
  const ushort* Ab = (const ushort*)Ap;

  f32x4 acc[MR][NR] = {};

  for (int k0 = 0; k0 < K; k0 += BK) {
    ushort aregs[AELEM] __attribute__((aligned(16)));
    if constexpr (AFP32) {
      const float* src = Af + (size_t)(bm0 + ar) * K + k0 + ak;
      #pragma unroll
      for (int c = 0; c < AELEM / 4; c++) {
        float4 v = *(const float4*)(src + c * 4);
        aregs[c * 4 + 0] = f2bf(v.x);
        aregs[c * 4 + 1] = f2bf(v.y);
        aregs[c * 4 + 2] = f2bf(v.z);
        aregs[c * 4 + 3] = f2bf(v.w);
      }
    } else {
      const ushort* src = Ab + (size_t)(bm0 + ar) * K + k0 + ak;
      #pragma unroll
      for (int c = 0; c < AELEM / 8; c++)
        *(short8*)&aregs[c * 8] = *(const short8*)(src + c * 8);
    }
    ushort bregs[BELEM] __attribute__((aligned(16)));
    {
      const ushort* src = BT + (size_t)(bn0 + br) * K + k0 + bk;
      #pragma unroll
      for (int c = 0; c < BELEM / 8; c++)
        *(short8*)&bregs[c * 8] = *(const short8*)(src + c * 8);
    }
    __syncthreads();
    #pragma unroll
    for (int c = 0; c < AELEM / 8; c++)
      *(short8*)&As[ar * LDSK + ak + c * 8] = *(short8*)&aregs[c * 8];
    #pragma unroll
    for (int c = 0; c < BELEM / 8; c++)
      *(short8*)&Bs[br * LDSK + bk + c * 8] = *(short8*)&bregs[c * 8];
    __syncthreads();

    const int kb = (l >> 4) * 8;
    const int rr = l & 15;
    short8 af[MR], bfv[NR];
    #pragma unroll
    for (int m = 0; m < MR; m++)
      af[m] = *(short8*)&As[(wr0 + m * 16 + rr) * LDSK + kb];
    #pragma unroll
    for (int n = 0; n < NR; n++)
      bfv[n] = *(short8*)&Bs[(wc0 + n * 16 + rr) * LDSK + kb];
    #pragma unroll
    for (int m = 0; m < MR; m++)
      #pragma unroll
      for (int n = 0; n < NR; n++)
        acc[m][n] = __builtin_amdgcn_mfma_f32_16x16x32_bf16(af[m], bfv[n], acc[m][n], 0, 0, 0);
  }

  #pragma unroll
  for (int m = 0; m < MR; m++) {
    const int row = bm0 + wr0 + m * 16 + (l >> 4) * 4;
    #pragma unroll
    for (int n = 0; n < NR; n++) {
      const int col = bn0 + wc0 + n * 16 + (l & 15);
      if constexpr (STORET) {
        ushort4 v;
        v.x = f2bf(acc[m][n][0]);
        v.y = f2bf(acc[m][n][1]);
        v.z = f2bf(acc[m][n][2]);
        v.w = f2bf(acc[m][n][3]);
        *(ushort4*)(Out + (size_t)col * M + row) = v;
      } else {
        const float bv = bias[col];
        #pragma unroll
        for (int r = 0; r < 4; r++) {
          float vv = fmaxf(acc[m][n][r] + bv, 0.0f);
          Out[(size_t)(row + r) * N + col] = f2bf(vv);
        }
      }
    }
  }
}

// s3[m][8] = h2[m][0:128] @ W3[128][8]
__global__ __launch_bounds__(256) void mm_small(
    const ushort* __restrict__ h2, const float* __restrict__ W3,
    float* __restrict__ s3) {
  __shared__ float w[NH2 * NCLS];
  for (int i = threadIdx.x; i < NH2 * NCLS; i += 256) w[i] = W3[i];
  __syncthreads();
  const int m = blockIdx.x * 256 + threadIdx.x;
  float acc[8] = {};
  const ushort* row = h2 + (size_t)m * NH2;
  #pragma unroll
  for (int c = 0; c < NH2 / 8; c++) {
    short8 v = *(const short8*)(row + c * 8);
    #pragma unroll
    for (int j = 0; j < 8; j++) {
      float h = bf2f((ushort)v[j]);
      const int k = c * 8 + j;
      #pragma unroll
      for (int n = 0; n < 8; n++) acc[n] += h * w[k * 8 + n];
    }
  }
  float4* o = (float4*)(s3 + (size_t)m * 8);
  o[0] = make_float4(acc[0], acc[1], acc[2], acc[3]);
  o[1] = make_float4(acc[4], acc[5], acc[6], acc[7]);
}

// out[m][8] = log_softmax(adj[m][:] @ s3 + b3). Block: 256 thr = 16 rows x 16 lanes.
__global__ __launch_bounds__(256) void final_adj(
    const float* __restrict__ adj, const float* __restrict__ s3,
    const float* __restrict__ b3, float* __restrict__ out) {
  const int t = threadIdx.x;
  const int g = t >> 4, j = t & 15;
  const int m = blockIdx.x * 16 + g;
  const float* arow = adj + (size_t)m * NROW;
  float acc[8] = {};
  #pragma unroll 4
  for (int k = j; k < NROW; k += 16) {
    float a = arow[k];
    float4 s0 = *(const float4*)(s3 + (size_t)k * 8);
    float4 s1 = *(const float4*)(s3 + (size_t)k * 8 + 4);
    acc[0] += a * s0.x; acc[1] += a * s0.y; acc[2] += a * s0.z; acc[3] += a * s0.w;
    acc[4] += a * s1.x; acc[5] += a * s1.y; acc[6] += a * s1.z; acc[7] += a * s1.w;
  }
  #pragma unroll
  for (int n = 0; n < 8; n++) {
    float v = acc[n];
    v += __shfl_xor(v, 1);
    v += __shfl_xor(v, 2);
    v += __shfl_xor(v, 4);
    v += __shfl_xor(v, 8);
    acc[n] = v + b3[n];
  }
  if (j == 0) {
    float mx = acc[0];
    #pragma unroll
    for (int n = 1; n < 8; n++) mx = fmaxf(mx, acc[n]);
    float s = 0.0f;
    #pragma unroll
    for (int n = 0; n < 8; n++) s += expf(acc[n] - mx);
    const float lse = logf(s);
    float4* o = (float4*)(out + (size_t)m * 8);
    o[0] = make_float4(acc[0] - mx - lse, acc[1] - mx - lse, acc[2] - mx - lse, acc[3] - mx - lse);
    o[1] = make_float4(acc[4] - mx - lse, acc[5] - mx - lse, acc[6] - mx - lse, acc[7] - mx - lse);
  }
}

extern "C" void kernel_launch(void* const* d_in, const int* in_sizes, int n_in,
                              void* d_out, int out_size, void* d_ws, size_t ws_size,
                              hipStream_t stream) {
  const float* x   = (const float*)d_in[0];
  const float* adj = (const float*)d_in[1];
  const float* W1  = (const float*)d_in[2];
  const float* b1  = (const float*)d_in[3];
  const float* W2  = (const float*)d_in[4];
  const float* b2  = (const float*)d_in[5];
  const float* W3  = (const float*)d_in[6];
  const float* b3  = (const float*)d_in[7];
  float* out = (float*)d_out;

  char* ws = (char*)d_ws;
  size_t off = 0;
  ushort* W1T = (ushort*)(ws + off); off += (size_t)NH1 * NFEATC * 2;      // [256][512]
  ushort* W2T = (ushort*)(ws + off); off += (size_t)NH2 * NH1 * 2;         // [128][256]
  ushort* s1T = (ushort*)(ws + off); off += (size_t)NH1 * NROW * 2;        // [256][16384]
  ushort* h1  = (ushort*)(ws + off); off += (size_t)NROW * NH1 * 2;        // [16384][256]
  ushort* s2T = (ushort*)(ws + off); off += (size_t)NH2 * NROW * 2;        // [128][16384]
  ushort* h2  = (ushort*)(ws + off); off += (size_t)NROW * NH2 * 2;        // [16384][128]
  float*  s3  = (float*)(ws + off);  off += (size_t)NROW * NCLS * 4;       // [16384][8]

  // weight transposes (bf16)
  transpose_conv<<<(NFEATC * NH1 + 255) / 256, 256, 0, stream>>>(W1, W1T, NFEATC, NH1);
  transpose_conv<<<(NH1 * NH2 + 255) / 256, 256, 0, stream>>>(W2, W2T, NH1, NH2);

  // s1T = (x @ W1)^T
  gemm_bf16<128, 128, 64, 64, true, true><<<dim3(NROW / 128, NH1 / 128), 256, 0, stream>>>(
      x, W1T, s1T, nullptr, NROW, NH1, NFEATC);
  // h1 = relu(adj @ s1 + b1)
  gemm_bf16<128, 128, 64, 64, true, false><<<dim3(NROW / 128, NH1 / 128), 256, 0, stream>>>(
      adj, s1T, h1, b1, NROW, NH1, NROW);
  // s2T = (h1 @ W2)^T
  gemm_bf16<64, 128, 32, 64, false, true><<<dim3(NROW / 64, NH2 / 128), 256, 0, stream>>>(
      h1, W2T, s2T, nullptr, NROW, NH2, NH1);
  // h2 = relu(adj @ s2 + b2)
  gemm_bf16<64, 128, 32, 64, true, false><<<dim3(NROW / 64, NH2 / 128), 256, 0, stream>>>(
      adj, s2T, h2, b2, NROW, NH2, NROW);
  // s3 = h2 @ W3
  mm_small<<<NROW / 256, 256, 0, stream>>>(h2, W3, s3);
  // out = log_softmax(adj @ s3 + b3)
  final_adj<<<NROW / 16, 256, 0, stream>>>(adj, s3, b3, out);
}

// Round 2
// 862.230 us; speedup vs baseline: 1.8905x; 1.8905x over previous
//
#include <hip/hip_runtime.h>
#include <hip/hip_bf16.h>

#define NROW 16384
#define NFEATC 512
#define NH1 256
#define NH2 128
#define NCLS 8

typedef __attribute__((ext_vector_type(8))) short short8;
typedef __attribute__((ext_vector_type(4))) float f32x4;

__device__ __forceinline__ ushort f2bf(float f) {
  union { float f; unsigned u; } v; v.f = f;
  unsigned r = v.u + 0x7FFFu + ((v.u >> 16) & 1u);
  return (ushort)(r >> 16);
}
__device__ __forceinline__ float bf2f(ushort h) {
  union { unsigned u; float f; } v; v.u = ((unsigned)h) << 16; return v.f;
}

// in [K][N] fp32 -> out [N][K] bf16
__global__ __launch_bounds__(256) void transpose_conv(
    const float* __restrict__ in, ushort* __restrict__ out, int K, int N) {
  int idx = blockIdx.x * 256 + threadIdx.x;
  if (idx < K * N) {
    int k = idx / N, n = idx % N;
    out[(size_t)n * K + k] = f2bf(in[idx]);
  }
}

// C = A[M][K] @ BT[N][K]^T, double-buffered pipeline, BK=64, 4 waves.
// OUTM==1: Out bf16 [N][M] (transposed store). OUTM==2: Out fp32 partial [ksl][M][N].
// Grid is flat 1-D (must be %8==0), decomposed flat -> (ksl, m, n) with n fastest.
template<int BM, int BN, int WM, int WN, int KSPLIT, bool AFP32, int OUTM>
__global__ __launch_bounds__(256, 2) void gemm_pipe(
    const void* __restrict__ Ap, const ushort* __restrict__ BT,
    void* __restrict__ Outp, const int nm, const int nn,
    const int M, const int N, const int K)
{
  constexpr int BK = 64, LDSK = BK + 8;
  constexpr int MR = WM / 16, NR = WN / 16;
  constexpr int nWc = BN / WN;
  static_assert((BM / WM) * (BN / WN) == 4, "4 waves");
  constexpr int AELEM = BM * BK / 256, ATPR = BK / AELEM;
  constexpr int BELEM = BN * BK / 256, BTPR = BK / BELEM;
  constexpr int A4 = AELEM / 4, A8 = AELEM / 8, B8 = BELEM / 8;

  __shared__ ushort As[2][BM * LDSK];
  __shared__ ushort Bs[2][BN * LDSK];

  const int t = threadIdx.x, l = t & 63, wid = t >> 6;
  const int wr0 = (wid / nWc) * WM, wc0 = (wid % nWc) * WN;

  // bijective XCD swizzle (gridDim.x % 8 == 0)
  const int cpx = gridDim.x >> 3;
  const int flat = (blockIdx.x & 7) * cpx + (blockIdx.x >> 3);
  const int n_blk = flat % nn;
  const int m_blk = (flat / nn) % nm;
  const int ksl = flat / (nn * nm);
  const int bm0 = m_blk * BM, bn0 = n_blk * BN;
  const int kper = K / KSPLIT;
  const int kbase = ksl * kper;
  const int NT = kper / BK;

  const int ar = t / ATPR, ak = (t % ATPR) * AELEM;
  const int br = t / BTPR, bk = (t % BTPR) * BELEM;

  const float*  Af = (const float*)Ap + (size_t)(bm0 + ar) * K + kbase + ak;
  const ushort* Ab = (const ushort*)Ap + (size_t)(bm0 + ar) * K + kbase + ak;
  const ushort* Bp = BT + (size_t)(bn0 + br) * K + kbase + bk;

  float4 aF[AFP32 ? A4 : 1];
  short8 aB8[AFP32 ? 1 : A8];
  short8 bB8[B8];
  f32x4 acc[MR][NR] = {};

  auto loadRegs = [&](int it) {
    const int ko = it * BK;
    if constexpr (AFP32) {
      #pragma unroll
      for (int c = 0; c < A4; c++) aF[c] = *(const float4*)(Af + ko + 4 * c);
    } else {
      #pragma unroll
      for (int c = 0; c < A8; c++) aB8[c] = *(const short8*)(Ab + ko + 8 * c);
    }
    #pragma unroll
    for (int c = 0; c < B8; c++) bB8[c] = *(const short8*)(Bp + ko + 8 * c);
  };
  auto writeLds = [&](int buf) {
    if constexpr (AFP32) {
      #pragma unroll
      for (int c = 0; c < A4; c++) {
        ushort4 v;
        v.x = f2bf(aF[c].x); v.y = f2bf(aF[c].y);
        v.z = f2bf(aF[c].z); v.w = f2bf(aF[c].w);
        *(ushort4*)&As[buf][ar * LDSK + ak + 4 * c] = v;
      }
    } else {
      #pragma unroll
      for (int c = 0; c < A8; c++)
        *(short8*)&As[buf][ar * LDSK + ak + 8 * c] = aB8[c];
    }
    #pragma unroll
    for (int c = 0; c < B8; c++)
      *(short8*)&Bs[buf][br * LDSK + bk + 8 * c] = bB8[c];
  };
  auto compute = [&](int buf) {
    const int rr = l & 15;
    #pragma unroll
    for (int kk = 0; kk < 2; kk++) {
      const int kb = kk * 32 + (l >> 4) * 8;
      short8 af[MR], bfv[NR];
      #pragma unroll
      for (int m = 0; m < MR; m++)
        af[m] = *(short8*)&As[buf][(wr0 + m * 16 + rr) * LDSK + kb];
      #pragma unroll
      for (int n = 0; n < NR; n++)
        bfv[n] = *(short8*)&Bs[buf][(wc0 + n * 16 + rr) * LDSK + kb];
      #pragma unroll
      for (int m = 0; m < MR; m++)
        #pragma unroll
        for (int n = 0; n < NR; n++)
          acc[m][n] = __builtin_amdgcn_mfma_f32_16x16x32_bf16(af[m], bfv[n], acc[m][n], 0, 0, 0);
    }
  };

  loadRegs(0);
  writeLds(0);
  __syncthreads();
  for (int it = 0; it < NT; it++) {
    const int cur = it & 1;
    if (it + 1 < NT) loadRegs(it + 1);
    compute(cur);
    if (it + 1 < NT) writeLds(cur ^ 1);
    __syncthreads();
  }

  #pragma unroll
  for (int m = 0; m < MR; m++) {
    const int row = bm0 + wr0 + m * 16 + (l >> 4) * 4;
    #pragma unroll
    for (int n = 0; n < NR; n++) {
      const int col = bn0 + wc0 + n * 16 + (l & 15);
      if constexpr (OUTM == 1) {
        ushort4 v;
        v.x = f2bf(acc[m][n][0]); v.y = f2bf(acc[m][n][1]);
        v.z = f2bf(acc[m][n][2]); v.w = f2bf(acc[m][n][3]);
        *(ushort4*)((ushort*)Outp + (size_t)col * M + row) = v;
      } else {
        float* o = (float*)Outp + (size_t)ksl * M * N;
        #pragma unroll
        for (int r = 0; r < 4; r++)
          o[(size_t)(row + r) * N + col] = acc[m][n][r];
      }
    }
  }
}

// out[M][N] bf16 = relu(sum_k part[k][M][N] + bias[col]); vectorized by 4
__global__ __launch_bounds__(256) void reduce_relu(
    const float* __restrict__ part, const float* __restrict__ bias,
    ushort* __restrict__ out, const int MN, const int N, const int KS) {
  const int i4 = (blockIdx.x * 256 + threadIdx.x) * 4;
  if (i4 >= MN) return;
  float4 s = *(const float4*)(part + i4);
  for (int k = 1; k < KS; k++) {
    float4 p = *(const float4*)(part + (size_t)k * MN + i4);
    s.x += p.x; s.y += p.y; s.z += p.z; s.w += p.w;
  }
  const int col = i4 % N;
  float4 b = *(const float4*)(bias + col);
  ushort4 v;
  v.x = f2bf(fmaxf(s.x + b.x, 0.0f));
  v.y = f2bf(fmaxf(s.y + b.y, 0.0f));
  v.z = f2bf(fmaxf(s.z + b.z, 0.0f));
  v.w = f2bf(fmaxf(s.w + b.w, 0.0f));
  *(ushort4*)(out + i4) = v;
}

// s3T[16][NROW] bf16 = (h2 @ W3)^T, rows 8..15 zero-padded
__global__ __launch_bounds__(256) void mm_small(
    const ushort* __restrict__ h2, const float* __restrict__ W3,
    ushort* __restrict__ s3T) {
  __shared__ float w[NH2 * NCLS];
  for (int i = threadIdx.x; i < NH2 * NCLS; i += 256) w[i] = W3[i];
  __syncthreads();
  const int m = blockIdx.x * 256 + threadIdx.x;
  float acc[8] = {};
  const ushort* row = h2 + (size_t)m * NH2;
  #pragma unroll
  for (int c = 0; c < NH2 / 8; c++) {
    short8 v = *(const short8*)(row + c * 8);
    #pragma unroll
    for (int j = 0; j < 8; j++) {
      float h = bf2f((ushort)v[j]);
      const int k = c * 8 + j;
      #pragma unroll
      for (int n = 0; n < 8; n++) acc[n] += h * w[k * 8 + n];
    }
  }
  #pragma unroll
  for (int n = 0; n < 8; n++) s3T[(size_t)n * NROW + m] = f2bf(acc[n]);
  #pragma unroll
  for (int n = 8; n < 16; n++) s3T[(size_t)n * NROW + m] = 0;
}

// part[4][NROW][16] fp32 += adj[M][K] @ s3T^T ; split-K=4, B frags direct from global (L2-hot)
__global__ __launch_bounds__(256, 2) void gemm_final(
    const float* __restrict__ adj, const ushort* __restrict__ s3T,
    float* __restrict__ part)
{
  constexpr int BM = 128, BK = 64, LDSK = BK + 8;
  __shared__ ushort As[2][BM * LDSK];
  const int t = threadIdx.x, l = t & 63, wid = t >> 6;
  const int wr0 = wid * 32;
  const int cpx = gridDim.x >> 3;
  const int flat = (blockIdx.x & 7) * cpx + (blockIdx.x >> 3);
  const int m_blk = flat & 127;
  const int ksl = flat >> 7;
  const int bm0 = m_blk * BM;
  const int kbase = ksl * (NROW / 4);
  constexpr int NT = (NROW / 4) / BK;
  const int ar = t >> 1, ak = (t & 1) * 32;
  const float* Af = adj + (size_t)(bm0 + ar) * NROW + kbase + ak;
  float4 aF[8];
  f32x4 acc[2] = {};

  auto loadA = [&](int it) {
    #pragma unroll
    for (int c = 0; c < 8; c++) aF[c] = *(const float4*)(Af + it * BK + 4 * c);
  };
  auto writeA = [&](int buf) {
    #pragma unroll
    for (int c = 0; c < 8; c++) {
      ushort4 v;
      v.x = f2bf(aF[c].x); v.y = f2bf(aF[c].y);
      v.z = f2bf(aF[c].z); v.w = f2bf(aF[c].w);
      *(ushort4*)&As[buf][ar * LDSK + ak + 4 * c] = v;
    }
  };
  const int rr = l & 15;
  auto comp = [&](int buf, int it) {
    #pragma unroll
    for (int kk = 0; kk < 2; kk++) {
      const int kb = kk * 32 + (l >> 4) * 8;
      short8 bfv = *(const short8*)(s3T + (size_t)rr * NROW + kbase + it * BK + kb);
      short8 af0 = *(short8*)&As[buf][(wr0 + rr) * LDSK + kb];
      short8 af1 = *(short8*)&As[buf][(wr0 + 16 + rr) * LDSK + kb];
      acc[0] = __builtin_amdgcn_mfma_f32_16x16x32_bf16(af0, bfv, acc[0], 0, 0, 0);
      acc[1] = __builtin_amdgcn_mfma_f32_16x16x32_bf16(af1, bfv, acc[1], 0, 0, 0);
    }
  };

  loadA(0); writeA(0); __syncthreads();
  for (int it = 0; it < NT; it++) {
    const int cur = it & 1;
    if (it + 1 < NT) loadA(it + 1);
    comp(cur, it);
    if (it + 1 < NT) writeA(cur ^ 1);
    __syncthreads();
  }

  float* op = part + (size_t)ksl * NROW * 16;
  #pragma unroll
  for (int m = 0; m < 2; m++) {
    const int row = bm0 + wr0 + m * 16 + (l >> 4) * 4;
    #pragma unroll
    for (int r = 0; r < 4; r++)
      op[(size_t)(row + r) * 16 + rr] = acc[m][r];
  }
}

// out[NROW][8] = log_softmax(sum_ksl part + b3)
__global__ __launch_bounds__(256) void final_reduce(
    const float* __restrict__ part, const float* __restrict__ b3,
    float* __restrict__ out) {
  const int m = blockIdx.x * 256 + threadIdx.x;
  float4 s0 = make_float4(0, 0, 0, 0), s1 = make_float4(0, 0, 0, 0);
  #pragma unroll
  for (int k = 0; k < 4; k++) {
    const float4* p = (const float4*)(part + ((size_t)k * NROW + m) * 16);
    float4 a = p[0], b = p[1];
    s0.x += a.x; s0.y += a.y; s0.z += a.z; s0.w += a.w;
    s1.x += b.x; s1.y += b.y; s1.z += b.z; s1.w += b.w;
  }
  float v[8];
  v[0] = s0.x + b3[0]; v[1] = s0.y + b3[1]; v[2] = s0.z + b3[2]; v[3] = s0.w + b3[3];
  v[4] = s1.x + b3[4]; v[5] = s1.y + b3[5]; v[6] = s1.z + b3[6]; v[7] = s1.w + b3[7];
  float mx = v[0];
  #pragma unroll
  for (int n = 1; n < 8; n++) mx = fmaxf(mx, v[n]);
  float s = 0.0f;
  #pragma unroll
  for (int n = 0; n < 8; n++) s += expf(v[n] - mx);
  const float lse = logf(s) + mx;
  float4* o = (float4*)(out + (size_t)m * 8);
  o[0] = make_float4(v[0] - lse, v[1] - lse, v[2] - lse, v[3] - lse);
  o[1] = make_float4(v[4] - lse, v[5] - lse, v[6] - lse, v[7] - lse);
}

extern "C" void kernel_launch(void* const* d_in, const int* in_sizes, int n_in,
                              void* d_out, int out_size, void* d_ws, size_t ws_size,
                              hipStream_t stream) {
  const float* x   = (const float*)d_in[0];
  const float* adj = (const float*)d_in[1];
  const float* W1  = (const float*)d_in[2];
  const float* b1  = (const float*)d_in[3];
  const float* W2  = (const float*)d_in[4];
  const float* b2  = (const float*)d_in[5];
  const float* W3  = (const float*)d_in[6];
  const float* b3  = (const float*)d_in[7];
  float* out = (float*)d_out;

  char* ws = (char*)d_ws;
  size_t off = 0;
  ushort* W1T = (ushort*)(ws + off); off += (size_t)NH1 * NFEATC * 2;   // 256 KB
  ushort* W2T = (ushort*)(ws + off); off += (size_t)NH2 * NH1 * 2;     // 64 KB
  ushort* s1T = (ushort*)(ws + off); off += (size_t)NH1 * NROW * 2;    // 8 MiB
  ushort* h1  = (ushort*)(ws + off); off += (size_t)NROW * NH1 * 2;    // 8 MiB
  ushort* s2T = (ushort*)(ws + off); off += (size_t)NH2 * NROW * 2;    // 4 MiB
  ushort* h2  = (ushort*)(ws + off); off += (size_t)NROW * NH2 * 2;    // 4 MiB
  ushort* s3T = (ushort*)(ws + off); off += (size_t)16 * NROW * 2;     // 512 KB
  float*  part = (float*)(ws + off); off += (size_t)2 * NROW * NH1 * 4; // 32 MiB (reused)

  transpose_conv<<<(NFEATC * NH1 + 255) / 256, 256, 0, stream>>>(W1, W1T, NFEATC, NH1);
  transpose_conv<<<(NH1 * NH2 + 255) / 256, 256, 0, stream>>>(W2, W2T, NH1, NH2);

  // s1T[256][16384] = (x @ W1)^T
  gemm_pipe<64, 128, 32, 64, 1, true, 1><<<512, 256, 0, stream>>>(
      x, W1T, s1T, 256, 2, NROW, NH1, NFEATC);
  // part[2][16384][256] = adj @ s1 (split-K=2)
  gemm_pipe<128, 128, 64, 64, 2, true, 2><<<512, 256, 0, stream>>>(
      adj, s1T, part, 128, 2, NROW, NH1, NROW);
  // h1 = relu(sum part + b1)
  reduce_relu<<<(NROW * NH1 / 4 + 255) / 256, 256, 0, stream>>>(
      part, b1, h1, NROW * NH1, NH1, 2);
  // s2T[128][16384] = (h1 @ W2)^T
  gemm_pipe<64, 128, 32, 64, 1, false, 1><<<256, 256, 0, stream>>>(
      h1, W2T, s2T, 256, 1, NROW, NH2, NH1);
  // part[4][16384][128] = adj @ s2 (split-K=4)
  gemm_pipe<128, 128, 64, 64, 4, true, 2><<<512, 256, 0, stream>>>(
      adj, s2T, part, 128, 1, NROW, NH2, NROW);
  // h2 = relu(sum part + b2)
  reduce_relu<<<(NROW * NH2 / 4 + 255) / 256, 256, 0, stream>>>(
      part, b2, h2, NROW * NH2, NH2, 4);
  // s3T[16][16384] = (h2 @ W3)^T (bf16, zero-padded to 16 cols)
  mm_small<<<NROW / 256, 256, 0, stream>>>(h2, W3, s3T);
  // part[4][16384][16] = adj @ s3 (split-K=4)
  gemm_final<<<512, 256, 0, stream>>>(adj, s3T, part);
  // out = log_softmax(sum part + b3)
  final_reduce<<<NROW / 256, 256, 0, stream>>>(part, b3, out);
}